// Round 7
// baseline (339.723 us; speedup 1.0000x reference)
//
#include <hip/hip_runtime.h>
#include <cstdint>
#include <cstddef>

#define D_IN   256
#define D_OUT  128
#define NB_MAX 256   // row buckets = (n+255)>>8 ; requires n <= 65535 (row/col in 16 bits)
#define NPASS  4
#define SEGW   32    // cols per pass

typedef short bf16x8 __attribute__((ext_vector_type(8)));
typedef float f32x4  __attribute__((ext_vector_type(4)));

union Frag { bf16x8 v; uint32_t u[4]; };

struct Branch {
  const float* X;
  const int*   idx;
  const float* val;
  uint16_t* H;          // 4 planes of [n][32] bf16 (col-segmented)
  int*   ptr;           // n+1
  int*   bucketTotal;   // NB_MAX
  int*   bucketBase;    // NB_MAX+1
  int*   bucketCur;     // NB_MAX
  uint64_t* kv2;        // ne: bucket-grouped (val32 | row16 | col16)
  uint32_t* csr4;       // ne: (val_bf16<<16 | col)
  float* out;
};

__device__ inline uint32_t cvt_pk_bf16(float lo, float hi) {
  uint32_t r;
  asm("v_cvt_pk_bf16_f32 %0, %1, %2" : "=v"(r) : "v"(lo), "v"(hi));
  return r;
}

// exclusive prefix over 256 threads (4 waves)
__device__ inline int block_scan256_excl(int v, int tid) {
  int lane = tid & 63, w = tid >> 6;
  int s = v;
  #pragma unroll
  for (int off = 1; off < 64; off <<= 1) {
    int t = __shfl_up(s, off);
    if (lane >= off) s += t;
  }
  __shared__ int wsum[4];
  if (lane == 63) wsum[w] = s;
  __syncthreads();
  int add = 0;
  #pragma unroll
  for (int i = 0; i < 4; ++i) add += (i < w) ? wsum[i] : 0;
  return s + add - v;
}

// ---------------- W prep: W[256][128] fp32 -> WT2 packed B-frags (bf16, RNE) ----------------
// WT2 unit (16B) index = n*32 + ks*4 + g ; holds W[ks*32+4g .. +3][n], W[ks*32+16+4g .. +3][n]
__global__ __launch_bounds__(256) void wprep2_kernel(const float* __restrict__ W,
                                                     uint16_t* __restrict__ WT2) {
  int n = blockIdx.x;    // 0..127
  int t = threadIdx.x;   // 0..255
  int ks = t >> 5, g = (t >> 3) & 3, j = t & 7;
  int k = ks * 32 + ((j < 4) ? (4 * g + j) : (16 + 4 * g + (j - 4)));
  uint32_t u = __float_as_uint(W[k * 128 + n]);
  WT2[(size_t)(n * 32 + ks * 4 + g) * 8 + j] =
      (uint16_t)((u + 0x7FFFu + ((u >> 16) & 1u)) >> 16);
}

// ---------------- GEMM: H = X @ W  (bf16 MFMA, fp32 acc, plane-segmented bf16 store) -------
// 4 waves/block, each wave independent: 16 rows x 64 cols. All A-loads hoisted.
__global__ __launch_bounds__(256, 4) void gemm_mfma_kernel(const uint16_t* __restrict__ WT2,
                                                           Branch b0, Branch b1, int n_rows) {
  Branch b = blockIdx.y ? b1 : b0;
  const int tid = threadIdx.x;
  const int w = tid >> 6, l = tid & 63;
  const int c = l & 15, g = l >> 4;
  const int rowtile = blockIdx.x * 2 + (w >> 1);
  const int nfh = w & 1;
  const int row0 = rowtile * 16;
  if (row0 >= n_rows) return;

  __shared__ uint16_t stg[4][16][72];

  int rA = row0 + c; if (rA > n_rows - 1) rA = n_rows - 1;
  const float4* Xr = (const float4*)(b.X + (size_t)rA * D_IN);

  // hoist the entire 16-row x 256-K A strip: 16 x float4 per lane
  float4 la[8][2];
  #pragma unroll
  for (int ks = 0; ks < 8; ++ks) {
    la[ks][0] = Xr[ks * 8 + g];
    la[ks][1] = Xr[ks * 8 + 4 + g];
  }

  const uint4* Bp = (const uint4*)WT2;
  f32x4 acc[4];
  #pragma unroll
  for (int nf = 0; nf < 4; ++nf) acc[nf] = (f32x4){0.f, 0.f, 0.f, 0.f};

  #pragma unroll
  for (int ks = 0; ks < 8; ++ks) {
    Frag A;
    A.u[0] = cvt_pk_bf16(la[ks][0].x, la[ks][0].y);
    A.u[1] = cvt_pk_bf16(la[ks][0].z, la[ks][0].w);
    A.u[2] = cvt_pk_bf16(la[ks][1].x, la[ks][1].y);
    A.u[3] = cvt_pk_bf16(la[ks][1].z, la[ks][1].w);
    #pragma unroll
    for (int nf = 0; nf < 4; ++nf) {
      int n = nfh * 64 + nf * 16 + c;
      uint4 bu = Bp[n * 32 + ks * 4 + g];
      Frag B;
      B.u[0] = bu.x; B.u[1] = bu.y; B.u[2] = bu.z; B.u[3] = bu.w;
      acc[nf] = __builtin_amdgcn_mfma_f32_16x16x32_bf16(A.v, B.v, acc[nf], 0, 0, 0);
    }
  }

  // epilogue (wave-local, no barrier): pack bf16 pairs into LDS, re-read coalesced
  #pragma unroll
  for (int nf = 0; nf < 4; ++nf)
    #pragma unroll
    for (int r = 0; r < 4; ++r) {
      float v = acc[nf][r];
      float o = __shfl_xor(v, 1);
      if (!(c & 1))
        *(uint32_t*)&stg[w][4 * g + r][nf * 16 + c] = cvt_pk_bf16(v, o);
    }
  // same-wave LDS readback (lgkmcnt ordering; no __syncthreads needed)
  {
    int rl = l >> 2, q = l & 3;
    int row_g = row0 + rl;
    if (row_g < n_rows) {
      #pragma unroll
      for (int h = 0; h < 2; ++h) {
        uint4 d = *(const uint4*)&stg[w][rl][h * 32 + q * 8];
        int seg = nfh * 2 + h;
        *(uint4*)(b.H + (size_t)seg * n_rows * SEGW + (size_t)row_g * SEGW + q * 8) = d;
      }
    }
  }
}

// ---------------- bucket-level counting ----------------
__global__ __launch_bounds__(256) void bucket_count_kernel(Branch b0, Branch b1, int ne, int nb) {
  Branch b = blockIdx.y ? b1 : b0;
  __shared__ int hist[NB_MAX];
  const int tid = threadIdx.x;
  const int base = blockIdx.x * 4096;
  if (tid < nb) hist[tid] = 0;
  __syncthreads();
  #pragma unroll
  for (int i = 0; i < 16; ++i) {
    int e = base + i * 256 + tid;
    if (e < ne) {
      int r = ((const int2*)b.idx)[e].x;
      atomicAdd(&hist[r >> 8], 1);
    }
  }
  __syncthreads();
  if (tid < nb) {
    int h = hist[tid];
    if (h) atomicAdd(&b.bucketTotal[tid], h);
  }
}

__global__ __launch_bounds__(256) void bucket_scan_kernel(Branch b0, Branch b1, int nb, int n, int ne) {
  Branch b = blockIdx.y ? b1 : b0;
  const int tid = threadIdx.x;
  int v = (tid < nb) ? b.bucketTotal[tid] : 0;
  int excl = block_scan256_excl(v, tid);
  if (tid <= nb) b.bucketBase[tid] = excl;
  if (tid < nb)  b.bucketCur[tid]  = excl;
  if (tid == 0)  b.ptr[n] = ne;
}

// ---------------- bin: bucket-grouped scatter ----------------
__global__ __launch_bounds__(256) void bin_kernel(Branch b0, Branch b1, int ne, int nb) {
  Branch b = blockIdx.y ? b1 : b0;
  __shared__ int hist[NB_MAX];
  __shared__ int lcur[NB_MAX];
  __shared__ int gbase[NB_MAX];
  const int tid = threadIdx.x;
  const int base = blockIdx.x * 4096;
  if (tid < nb) hist[tid] = 0;
  __syncthreads();
  uint64_t kv2[16];
  int bkt[16];
  #pragma unroll
  for (int i = 0; i < 16; ++i) {
    int e = base + i * 256 + tid;
    bkt[i] = -1;
    if (e < ne) {
      int2 rc = ((const int2*)b.idx)[e];
      uint32_t v = __float_as_uint(b.val[e]);
      kv2[i] = ((uint64_t)v << 32) | ((uint32_t)rc.x << 16) | (uint32_t)rc.y;
      bkt[i] = rc.x >> 8;
      atomicAdd(&hist[bkt[i]], 1);
    }
  }
  __syncthreads();
  if (tid < nb) {
    int h = hist[tid];
    gbase[tid] = h ? atomicAdd(&b.bucketCur[tid], h) : 0;
    lcur[tid] = 0;
  }
  __syncthreads();
  #pragma unroll
  for (int i = 0; i < 16; ++i) {
    if (bkt[i] >= 0) {
      int dst = gbase[bkt[i]] + atomicAdd(&lcur[bkt[i]], 1);
      b.kv2[dst] = kv2[i];
    }
  }
}

// ---------------- per-bucket CSR finalize: 4B entries (val_bf16<<16 | col) ----------------
__global__ __launch_bounds__(256) void bucket_csr_kernel(Branch b0, Branch b1, int n) {
  Branch b = blockIdx.y ? b1 : b0;
  const int bkt = blockIdx.x;
  const int tid = threadIdx.x;
  const int beg = b.bucketBase[bkt], end = b.bucketBase[bkt + 1];
  __shared__ int hist[256];
  __shared__ int cur[256];
  hist[tid] = 0;
  __syncthreads();
  for (int e = beg + tid; e < end; e += 256)
    atomicAdd(&hist[(int)((b.kv2[e] >> 16) & 0xFF)], 1);
  __syncthreads();
  int v = hist[tid];
  int excl = block_scan256_excl(v, tid);
  cur[tid] = beg + excl;
  int row = bkt * 256 + tid;
  if (row < n) b.ptr[row] = beg + excl;
  __syncthreads();
  for (int e = beg + tid; e < end; e += 256) {
    uint64_t kv2 = b.kv2[e];
    int r = (int)((kv2 >> 16) & 0xFF);
    uint32_t u = (uint32_t)(kv2 >> 32);
    uint32_t vbf = (u + 0x7FFFu + ((u >> 16) & 1u)) & 0xFFFF0000u;  // RNE bf16 in high16
    int pos = atomicAdd(&cur[r], 1);
    b.csr4[pos] = vbf | (uint32_t)(kv2 & 0xFFFFu);
  }
}

// ---------------- per-row gather + relu, one col-segment per launch ----------------
// linear grid; XCD routing: branch = ((bid & 7) >> 2)  [XCD = bid % 8]
// csr/ptr streamed with non-temporal loads so the H plane stays L2-resident.
__global__ __launch_bounds__(256) void gather_pass_kernel(Branch b0, Branch b1, int n_rows,
                                                          int pass) {
  const int bid = blockIdx.x;
  const int br  = (bid & 7) >> 2;
  const int local = (bid >> 3) * 4 + (bid & 3);
  Branch b = br ? b1 : b0;
  const int tid = threadIdx.x;
  const int lane8 = tid & 7;
  const int row = local * 32 + (tid >> 3);
  if (row >= n_rows) return;

  const uint16_t* Hp = b.H + (size_t)pass * n_rows * SEGW;
  int beg = __builtin_nontemporal_load(&b.ptr[row]);
  int end = __builtin_nontemporal_load(&b.ptr[row + 1]);
  float4 acc = make_float4(0.f, 0.f, 0.f, 0.f);

  auto fma_edge = [&](uint32_t e4) {
    int c = (int)(e4 & 0xFFFFu);
    float v = __uint_as_float(e4 & 0xFFFF0000u);   // bf16 val in high bits
    uint2 h = *(const uint2*)(Hp + (size_t)c * SEGW + lane8 * 4);
    float h0 = __uint_as_float(h.x << 16);
    float h1 = __uint_as_float(h.x & 0xFFFF0000u);
    float h2 = __uint_as_float(h.y << 16);
    float h3 = __uint_as_float(h.y & 0xFFFF0000u);
    acc.x = fmaf(h0, v, acc.x); acc.y = fmaf(h1, v, acc.y);
    acc.z = fmaf(h2, v, acc.z); acc.w = fmaf(h3, v, acc.w);
  };

  int e = beg;
  for (; e + 4 <= end; e += 4) {
    uint32_t kA = __builtin_nontemporal_load(&b.csr4[e + 0]);
    uint32_t kB = __builtin_nontemporal_load(&b.csr4[e + 1]);
    uint32_t kC = __builtin_nontemporal_load(&b.csr4[e + 2]);
    uint32_t kD = __builtin_nontemporal_load(&b.csr4[e + 3]);
    fma_edge(kA); fma_edge(kB); fma_edge(kC); fma_edge(kD);
  }
  for (; e < end; ++e) fma_edge(__builtin_nontemporal_load(&b.csr4[e]));

  float4 o;
  o.x = fmaxf(acc.x, 0.f); o.y = fmaxf(acc.y, 0.f);
  o.z = fmaxf(acc.z, 0.f); o.w = fmaxf(acc.w, 0.f);
  *(float4*)&b.out[(size_t)row * D_OUT + pass * SEGW + lane8 * 4] = o;
}

extern "C" void kernel_launch(void* const* d_in, const int* in_sizes, int n_in,
                              void* d_out, int out_size, void* d_ws, size_t ws_size,
                              hipStream_t stream) {
  const float* inp_s = (const float*)d_in[0];
  const float* inp_t = (const float*)d_in[1];
  const int*   idx_s = (const int*)d_in[2];
  const float* val_s = (const float*)d_in[3];
  const int*   idx_t = (const int*)d_in[4];
  const float* val_t = (const float*)d_in[5];
  const float* W     = (const float*)d_in[6];
  float* out = (float*)d_out;

  const int n  = in_sizes[0] / D_IN;   // 50000
  const int ne = in_sizes[3];          // 1600000
  const int nb = (n + 255) >> 8;       // 196

  char* p = (char*)d_ws;
  auto alloc = [&](size_t bytes) -> char* {
    char* r = p;
    p += (bytes + 255) & ~(size_t)255;
    return r;
  };
  uint16_t* H_s    = (uint16_t*)alloc((size_t)n * D_OUT * 2);
  uint16_t* H_t    = (uint16_t*)alloc((size_t)n * D_OUT * 2);
  uint16_t* WT2    = (uint16_t*)alloc((size_t)128 * 256 * 2);
  int* ptr_s       = (int*)alloc((size_t)(n + 1) * 4);
  int* ptr_t       = (int*)alloc((size_t)(n + 1) * 4);
  int* btotal      = (int*)alloc((size_t)2 * NB_MAX * 4);
  int* btotal_s    = btotal;
  int* btotal_t    = btotal + NB_MAX;
  int* bbase_s     = (int*)alloc((size_t)(NB_MAX + 1) * 4);
  int* bbase_t     = (int*)alloc((size_t)(NB_MAX + 1) * 4);
  int* bcur_s      = (int*)alloc(NB_MAX * 4);
  int* bcur_t      = (int*)alloc(NB_MAX * 4);
  uint64_t* kv2_s  = (uint64_t*)alloc((size_t)ne * 8);
  uint64_t* kv2_t  = (uint64_t*)alloc((size_t)ne * 8);
  uint32_t* c4_s   = (uint32_t*)alloc((size_t)ne * 4);
  uint32_t* c4_t   = (uint32_t*)alloc((size_t)ne * 4);

  Branch bs = { inp_s, idx_s, val_s, H_s, ptr_s, btotal_s, bbase_s, bcur_s, kv2_s, c4_s, out };
  Branch bt = { inp_t, idx_t, val_t, H_t, ptr_t, btotal_t, bbase_t, bcur_t, kv2_t, c4_t,
                out + (size_t)n * D_OUT };

  const int nblkE = (ne + 4095) / 4096;
  const int bpb   = (((n + 31) / 32) + 3) & ~3;       // gather blocks per branch, %4==0
  const int tiles = (n + 15) / 16;                    // 16-row tiles per branch

  hipMemsetAsync(btotal, 0, (size_t)2 * NB_MAX * 4, stream);
  wprep2_kernel<<<dim3(128), 256, 0, stream>>>(W, WT2);
  gemm_mfma_kernel<<<dim3((tiles + 1) / 2, 2), 256, 0, stream>>>(WT2, bs, bt, n);
  bucket_count_kernel<<<dim3(nblkE, 2), 256, 0, stream>>>(bs, bt, ne, nb);
  bucket_scan_kernel<<<dim3(1, 2), 256, 0, stream>>>(bs, bt, nb, n, ne);
  bin_kernel<<<dim3(nblkE, 2), 256, 0, stream>>>(bs, bt, ne, nb);
  bucket_csr_kernel<<<dim3(nb, 2), 256, 0, stream>>>(bs, bt, n);
  for (int pass = 0; pass < NPASS; ++pass)
    gather_pass_kernel<<<dim3(2 * bpb), 256, 0, stream>>>(bs, bt, n, pass);
}

// Round 8
// 214.226 us; speedup vs baseline: 1.5858x; 1.5858x over previous
//
#include <hip/hip_runtime.h>
#include <cstdint>
#include <cstddef>

#define D_IN   256
#define D_OUT  128
#define NB_MAX 256   // row buckets = (n+255)>>8 ; requires n <= 65535 (row/col in 16 bits)

typedef short bf16x8 __attribute__((ext_vector_type(8)));
typedef float f32x4  __attribute__((ext_vector_type(4)));

union Frag { bf16x8 v; uint32_t u[4]; };

struct Branch {
  const float* X;
  const int*   idx;
  const float* val;
  uint16_t* H;          // flat [n][128] bf16
  int*   ptr;           // n+1
  int*   bucketTotal;   // NB_MAX
  int*   bucketBase;    // NB_MAX+1
  int*   bucketCur;     // NB_MAX
  uint64_t* kv2;        // ne: bucket-grouped (val32 | row16 | col16)
  uint32_t* csr4;       // ne: (val_bf16<<16 | col)
  float* out;
};

__device__ inline uint32_t cvt_pk_bf16(float lo, float hi) {
  uint32_t r;
  asm("v_cvt_pk_bf16_f32 %0, %1, %2" : "=v"(r) : "v"(lo), "v"(hi));
  return r;
}

// exclusive prefix over 256 threads (4 waves)
__device__ inline int block_scan256_excl(int v, int tid) {
  int lane = tid & 63, w = tid >> 6;
  int s = v;
  #pragma unroll
  for (int off = 1; off < 64; off <<= 1) {
    int t = __shfl_up(s, off);
    if (lane >= off) s += t;
  }
  __shared__ int wsum[4];
  if (lane == 63) wsum[w] = s;
  __syncthreads();
  int add = 0;
  #pragma unroll
  for (int i = 0; i < 4; ++i) add += (i < w) ? wsum[i] : 0;
  return s + add - v;
}

// ---------------- W prep: W[256][128] fp32 -> WT3 B-frag units (bf16, RNE) ----------------
// 16B unit index = (ks*4+g)*128 + n ; element j: k = ks*32 + (j<4 ? 4g+j : 16+4g+j-4)
__global__ __launch_bounds__(256) void wprep3_kernel(const float* __restrict__ W,
                                                     uint16_t* __restrict__ WT3) {
  int n = blockIdx.x;    // 0..127
  int t = threadIdx.x;   // 0..255
  int ks = t >> 5, g = (t >> 3) & 3, j = t & 7;
  int k = ks * 32 + ((j < 4) ? (4 * g + j) : (16 + 4 * g + (j - 4)));
  uint32_t u = __float_as_uint(W[k * 128 + n]);
  WT3[(size_t)((ks * 4 + g) * 128 + n) * 8 + j] =
      (uint16_t)((u + 0x7FFFu + ((u >> 16) & 1u)) >> 16);
}

// ---------------- GEMM: H = X @ W  (bf16 MFMA, global_load_lds-staged X) ----------------
// block = 4 waves, tile 128 rows x 128 cols, K-chunks of 32 double-buffered in LDS.
__global__ __launch_bounds__(256, 3) void gemm_mfma_kernel(const uint16_t* __restrict__ WT3,
                                                           Branch b0, Branch b1, int n_rows) {
  Branch b = blockIdx.y ? b1 : b0;
  const int t = threadIdx.x;
  const int w = t >> 6, l = t & 63;
  const int c = l & 15, g = l >> 4;
  const int row0 = blockIdx.x * 128;

  __shared__ uint8_t sX[2][16384];   // [buf][128 rows][32 k] fp32, 16B-slot XOR-swizzled

  // stage chunk ks into buf: linear LDS dest (DMA), inverse-swizzled global source
  auto stage = [&](int ks, int buf) {
    #pragma unroll
    for (int i = 0; i < 4; ++i) {
      int row = i * 32 + (t >> 3);
      int gr = row0 + row; if (gr > n_rows - 1) gr = n_rows - 1;
      int kb = ((t & 7) * 16) ^ ((row & 7) << 4);   // swizzled byte within 128B row
      const float* src = b.X + (size_t)gr * D_IN + ks * 32 + (kb >> 2);
      __builtin_amdgcn_global_load_lds(
          (const __attribute__((address_space(1))) uint32_t*)src,
          (__attribute__((address_space(3))) uint32_t*)&sX[buf][i * 4096 + t * 16],
          16, 0, 0);
    }
  };

  const uint4* Bp = (const uint4*)WT3;

  f32x4 acc[2][8];
  #pragma unroll
  for (int i = 0; i < 2; ++i)
    #pragma unroll
    for (int j = 0; j < 8; ++j) acc[i][j] = (f32x4){0.f, 0.f, 0.f, 0.f};

  stage(0, 0);
  asm volatile("s_waitcnt vmcnt(0)" ::: "memory");
  __syncthreads();

  for (int ks = 0; ks < 8; ++ks) {
    int buf = ks & 1;
    // B loads first (oldest vm ops), so compiler waits on B keep the stage in flight
    uint4 bu[8];
    #pragma unroll
    for (int nf = 0; nf < 8; ++nf)
      bu[nf] = Bp[(ks * 4 + g) * 128 + nf * 16 + c];
    if (ks < 7) stage(ks + 1, buf ^ 1);

    // A fragments from swizzled LDS
    Frag A[2];
    #pragma unroll
    for (int rf = 0; rf < 2; ++rf) {
      int row = w * 32 + rf * 16 + c;
      const uint8_t* base = &sX[buf][row * 128];
      int swz = (row & 7) << 4;
      float4 x0 = *(const float4*)(base + ((g * 16) ^ swz));
      float4 x1 = *(const float4*)(base + ((64 + g * 16) ^ swz));
      A[rf].u[0] = cvt_pk_bf16(x0.x, x0.y);
      A[rf].u[1] = cvt_pk_bf16(x0.z, x0.w);
      A[rf].u[2] = cvt_pk_bf16(x1.x, x1.y);
      A[rf].u[3] = cvt_pk_bf16(x1.z, x1.w);
    }

    #pragma unroll
    for (int nf = 0; nf < 8; ++nf) {
      Frag B;
      B.u[0] = bu[nf].x; B.u[1] = bu[nf].y; B.u[2] = bu[nf].z; B.u[3] = bu[nf].w;
      acc[0][nf] = __builtin_amdgcn_mfma_f32_16x16x32_bf16(A[0].v, B.v, acc[0][nf], 0, 0, 0);
      acc[1][nf] = __builtin_amdgcn_mfma_f32_16x16x32_bf16(A[1].v, B.v, acc[1][nf], 0, 0, 0);
    }

    if (ks < 7) {
      asm volatile("s_waitcnt vmcnt(0)" ::: "memory");
      __syncthreads();
    }
  }

  // epilogue: direct packed-bf16 stores, no LDS (uint2 = 4 consecutive cols)
  #pragma unroll
  for (int rf = 0; rf < 2; ++rf)
    #pragma unroll
    for (int nf = 0; nf < 8; ++nf)
      #pragma unroll
      for (int r = 0; r < 4; ++r) {
        float v = acc[rf][nf][r];
        float o = __shfl_xor(v, 1);
        uint32_t pk = cvt_pk_bf16(v, o);       // valid at even c: cols (c, c+1)
        uint32_t pk2 = __shfl_xor(pk, 2);      // partner: cols (c+2, c+3)
        int row_g = row0 + w * 32 + rf * 16 + 4 * g + r;
        if ((c & 3) == 0 && row_g < n_rows) {
          uint2 d; d.x = pk; d.y = pk2;
          *(uint2*)(b.H + (size_t)row_g * D_OUT + nf * 16 + c) = d;
        }
      }
}

// ---------------- bucket-level counting ----------------
__global__ __launch_bounds__(256) void bucket_count_kernel(Branch b0, Branch b1, int ne, int nb) {
  Branch b = blockIdx.y ? b1 : b0;
  __shared__ int hist[NB_MAX];
  const int tid = threadIdx.x;
  const int base = blockIdx.x * 4096;
  if (tid < nb) hist[tid] = 0;
  __syncthreads();
  #pragma unroll
  for (int i = 0; i < 16; ++i) {
    int e = base + i * 256 + tid;
    if (e < ne) {
      int r = ((const int2*)b.idx)[e].x;
      atomicAdd(&hist[r >> 8], 1);
    }
  }
  __syncthreads();
  if (tid < nb) {
    int h = hist[tid];
    if (h) atomicAdd(&b.bucketTotal[tid], h);
  }
}

__global__ __launch_bounds__(256) void bucket_scan_kernel(Branch b0, Branch b1, int nb, int n, int ne) {
  Branch b = blockIdx.y ? b1 : b0;
  const int tid = threadIdx.x;
  int v = (tid < nb) ? b.bucketTotal[tid] : 0;
  int excl = block_scan256_excl(v, tid);
  if (tid <= nb) b.bucketBase[tid] = excl;
  if (tid < nb)  b.bucketCur[tid]  = excl;
  if (tid == 0)  b.ptr[n] = ne;
}

// ---------------- bin: bucket-grouped scatter ----------------
__global__ __launch_bounds__(256) void bin_kernel(Branch b0, Branch b1, int ne, int nb) {
  Branch b = blockIdx.y ? b1 : b0;
  __shared__ int hist[NB_MAX];
  __shared__ int lcur[NB_MAX];
  __shared__ int gbase[NB_MAX];
  const int tid = threadIdx.x;
  const int base = blockIdx.x * 4096;
  if (tid < nb) hist[tid] = 0;
  __syncthreads();
  uint64_t kv2[16];
  int bkt[16];
  #pragma unroll
  for (int i = 0; i < 16; ++i) {
    int e = base + i * 256 + tid;
    bkt[i] = -1;
    if (e < ne) {
      int2 rc = ((const int2*)b.idx)[e];
      uint32_t v = __float_as_uint(b.val[e]);
      kv2[i] = ((uint64_t)v << 32) | ((uint32_t)rc.x << 16) | (uint32_t)rc.y;
      bkt[i] = rc.x >> 8;
      atomicAdd(&hist[bkt[i]], 1);
    }
  }
  __syncthreads();
  if (tid < nb) {
    int h = hist[tid];
    gbase[tid] = h ? atomicAdd(&b.bucketCur[tid], h) : 0;
    lcur[tid] = 0;
  }
  __syncthreads();
  #pragma unroll
  for (int i = 0; i < 16; ++i) {
    if (bkt[i] >= 0) {
      int dst = gbase[bkt[i]] + atomicAdd(&lcur[bkt[i]], 1);
      b.kv2[dst] = kv2[i];
    }
  }
}

// ---------------- per-bucket CSR finalize: 4B entries (val_bf16<<16 | col) ----------------
__global__ __launch_bounds__(256) void bucket_csr_kernel(Branch b0, Branch b1, int n) {
  Branch b = blockIdx.y ? b1 : b0;
  const int bkt = blockIdx.x;
  const int tid = threadIdx.x;
  const int beg = b.bucketBase[bkt], end = b.bucketBase[bkt + 1];
  __shared__ int hist[256];
  __shared__ int cur[256];
  hist[tid] = 0;
  __syncthreads();
  for (int e = beg + tid; e < end; e += 256)
    atomicAdd(&hist[(int)((b.kv2[e] >> 16) & 0xFF)], 1);
  __syncthreads();
  int v = hist[tid];
  int excl = block_scan256_excl(v, tid);
  cur[tid] = beg + excl;
  int row = bkt * 256 + tid;
  if (row < n) b.ptr[row] = beg + excl;
  __syncthreads();
  for (int e = beg + tid; e < end; e += 256) {
    uint64_t kv2 = b.kv2[e];
    int r = (int)((kv2 >> 16) & 0xFF);
    uint32_t u = (uint32_t)(kv2 >> 32);
    uint32_t vbf = (u + 0x7FFFu + ((u >> 16) & 1u)) & 0xFFFF0000u;  // RNE bf16 in high16
    int pos = atomicAdd(&cur[r], 1);
    b.csr4[pos] = vbf | (uint32_t)(kv2 & 0xFFFFu);
  }
}

// ---------------- per-row gather + relu (single pass, flat H) ----------------
// 32 lanes per row, 8 rows per block; XCD routing: branch = (bid&7)>>2  [XCD = bid % 8]
__global__ __launch_bounds__(256) void gather_kernel(Branch b0, Branch b1, int n_rows) {
  const int bid = blockIdx.x;
  const int br  = (bid & 7) >> 2;
  const int local = (bid >> 3) * 4 + (bid & 3);
  Branch b = br ? b1 : b0;
  int row = local * 8 + (threadIdx.x >> 5);
  if (row >= n_rows) return;
  int lane2 = (threadIdx.x & 31) * 2;
  const uint32_t* H32 = (const uint32_t*)b.H;
  int beg = b.ptr[row], end = b.ptr[row + 1];
  float4 acc = make_float4(0.f, 0.f, 0.f, 0.f);

  auto fma_edge = [&](uint32_t e4) {
    int c = (int)(e4 & 0xFFFFu);
    float v = __uint_as_float(e4 & 0xFFFF0000u);   // bf16 val in high bits
    uint2 h = *(const uint2*)(H32 + (size_t)c * 64 + lane2);
    float h0 = __uint_as_float(h.x << 16);
    float h1 = __uint_as_float(h.x & 0xFFFF0000u);
    float h2 = __uint_as_float(h.y << 16);
    float h3 = __uint_as_float(h.y & 0xFFFF0000u);
    acc.x = fmaf(h0, v, acc.x); acc.y = fmaf(h1, v, acc.y);
    acc.z = fmaf(h2, v, acc.z); acc.w = fmaf(h3, v, acc.w);
  };

  int e = beg;
  for (; e + 8 <= end; e += 8) {
    uint32_t k0 = b.csr4[e + 0], k1 = b.csr4[e + 1];
    uint32_t k2 = b.csr4[e + 2], k3 = b.csr4[e + 3];
    uint32_t k4 = b.csr4[e + 4], k5 = b.csr4[e + 5];
    uint32_t k6 = b.csr4[e + 6], k7 = b.csr4[e + 7];
    fma_edge(k0); fma_edge(k1); fma_edge(k2); fma_edge(k3);
    fma_edge(k4); fma_edge(k5); fma_edge(k6); fma_edge(k7);
  }
  for (; e < end; ++e) fma_edge(b.csr4[e]);

  float4 o;
  o.x = fmaxf(acc.x, 0.f); o.y = fmaxf(acc.y, 0.f);
  o.z = fmaxf(acc.z, 0.f); o.w = fmaxf(acc.w, 0.f);
  *(float4*)&b.out[(size_t)row * D_OUT + (threadIdx.x & 31) * 4] = o;
}

extern "C" void kernel_launch(void* const* d_in, const int* in_sizes, int n_in,
                              void* d_out, int out_size, void* d_ws, size_t ws_size,
                              hipStream_t stream) {
  const float* inp_s = (const float*)d_in[0];
  const float* inp_t = (const float*)d_in[1];
  const int*   idx_s = (const int*)d_in[2];
  const float* val_s = (const float*)d_in[3];
  const int*   idx_t = (const int*)d_in[4];
  const float* val_t = (const float*)d_in[5];
  const float* W     = (const float*)d_in[6];
  float* out = (float*)d_out;

  const int n  = in_sizes[0] / D_IN;   // 50000
  const int ne = in_sizes[3];          // 1600000
  const int nb = (n + 255) >> 8;       // 196

  char* p = (char*)d_ws;
  auto alloc = [&](size_t bytes) -> char* {
    char* r = p;
    p += (bytes + 255) & ~(size_t)255;
    return r;
  };
  uint16_t* H_s    = (uint16_t*)alloc((size_t)n * D_OUT * 2);
  uint16_t* H_t    = (uint16_t*)alloc((size_t)n * D_OUT * 2);
  uint16_t* WT3    = (uint16_t*)alloc((size_t)128 * 256 * 2);
  int* ptr_s       = (int*)alloc((size_t)(n + 1) * 4);
  int* ptr_t       = (int*)alloc((size_t)(n + 1) * 4);
  int* btotal      = (int*)alloc((size_t)2 * NB_MAX * 4);
  int* btotal_s    = btotal;
  int* btotal_t    = btotal + NB_MAX;
  int* bbase_s     = (int*)alloc((size_t)(NB_MAX + 1) * 4);
  int* bbase_t     = (int*)alloc((size_t)(NB_MAX + 1) * 4);
  int* bcur_s      = (int*)alloc(NB_MAX * 4);
  int* bcur_t      = (int*)alloc(NB_MAX * 4);
  uint64_t* kv2_s  = (uint64_t*)alloc((size_t)ne * 8);
  uint64_t* kv2_t  = (uint64_t*)alloc((size_t)ne * 8);
  uint32_t* c4_s   = (uint32_t*)alloc((size_t)ne * 4);
  uint32_t* c4_t   = (uint32_t*)alloc((size_t)ne * 4);

  Branch bs = { inp_s, idx_s, val_s, H_s, ptr_s, btotal_s, bbase_s, bcur_s, kv2_s, c4_s, out };
  Branch bt = { inp_t, idx_t, val_t, H_t, ptr_t, btotal_t, bbase_t, bcur_t, kv2_t, c4_t,
                out + (size_t)n * D_OUT };

  const int nblkE = (ne + 4095) / 4096;
  const int bpb   = (((n + 7) / 8) + 3) & ~3;   // gather blocks per branch, %4==0

  hipMemsetAsync(btotal, 0, (size_t)2 * NB_MAX * 4, stream);
  wprep3_kernel<<<dim3(128), 256, 0, stream>>>(W, WT3);
  gemm_mfma_kernel<<<dim3((n + 127) / 128, 2), 256, 0, stream>>>(WT3, bs, bt, n);
  bucket_count_kernel<<<dim3(nblkE, 2), 256, 0, stream>>>(bs, bt, ne, nb);
  bucket_scan_kernel<<<dim3(1, 2), 256, 0, stream>>>(bs, bt, nb, n, ne);
  bin_kernel<<<dim3(nblkE, 2), 256, 0, stream>>>(bs, bt, ne, nb);
  bucket_csr_kernel<<<dim3(nb, 2), 256, 0, stream>>>(bs, bt, n);
  gather_kernel<<<dim3(2 * bpb), 256, 0, stream>>>(bs, bt, n);
}

// Round 9
// 211.474 us; speedup vs baseline: 1.6065x; 1.0130x over previous
//
#include <hip/hip_runtime.h>
#include <cstdint>
#include <cstddef>

#define D_IN   256
#define D_OUT  128
#define NB_MAX 256   // row buckets = (n+255)>>8 ; requires n <= 65535 (row/col in 16 bits)

typedef short bf16x8 __attribute__((ext_vector_type(8)));
typedef float f32x4  __attribute__((ext_vector_type(4)));

union Frag { bf16x8 v; uint32_t u[4]; };

struct Branch {
  const float* X;
  const int*   idx;
  const float* val;
  uint16_t* H;          // flat [n][128] bf16
  int*   ptr;           // n+1
  int*   bucketTotal;   // NB_MAX
  int*   bucketBase;    // NB_MAX+1
  int*   bucketCur;     // NB_MAX
  uint64_t* kv2;        // ne: bucket-grouped (val32 | row16 | col16)
  uint32_t* csr4;       // ne: (val_bf16<<16 | col)
  float* out;
};

__device__ inline uint32_t cvt_pk_bf16(float lo, float hi) {
  uint32_t r;
  asm("v_cvt_pk_bf16_f32 %0, %1, %2" : "=v"(r) : "v"(lo), "v"(hi));
  return r;
}

// exclusive prefix over 256 threads (4 waves)
__device__ inline int block_scan256_excl(int v, int tid) {
  int lane = tid & 63, w = tid >> 6;
  int s = v;
  #pragma unroll
  for (int off = 1; off < 64; off <<= 1) {
    int t = __shfl_up(s, off);
    if (lane >= off) s += t;
  }
  __shared__ int wsum[4];
  if (lane == 63) wsum[w] = s;
  __syncthreads();
  int add = 0;
  #pragma unroll
  for (int i = 0; i < 4; ++i) add += (i < w) ? wsum[i] : 0;
  return s + add - v;
}

// ---------------- W prep: W[256][128] fp32 -> WT3 B-frag units (bf16, RNE) ----------------
__global__ __launch_bounds__(256) void wprep3_kernel(const float* __restrict__ W,
                                                     uint16_t* __restrict__ WT3) {
  int n = blockIdx.x;    // 0..127
  int t = threadIdx.x;   // 0..255
  int ks = t >> 5, g = (t >> 3) & 3, j = t & 7;
  int k = ks * 32 + ((j < 4) ? (4 * g + j) : (16 + 4 * g + (j - 4)));
  uint32_t u = __float_as_uint(W[k * 128 + n]);
  WT3[(size_t)((ks * 4 + g) * 128 + n) * 8 + j] =
      (uint16_t)((u + 0x7FFFu + ((u >> 16) & 1u)) >> 16);
}

// ---------------- fused: z=0 GEMM tile, z=1 bucket_count ----------------
__global__ __launch_bounds__(256, 3) void gemm_count_kernel(const uint16_t* __restrict__ WT3,
                                                            Branch b0, Branch b1,
                                                            int n_rows, int ne, int nb) {
  Branch b = blockIdx.y ? b1 : b0;
  const int t = threadIdx.x;

  __shared__ uint8_t sX[2][16384];   // gemm: [buf][128 rows][32 k] fp32, 16B-slot XOR-swizzled
  __shared__ int hist[NB_MAX];       // count

  if (blockIdx.z == 1) {
    // ---- bucket_count body ----
    const int base = blockIdx.x * 4096;
    if (t < nb) hist[t] = 0;
    __syncthreads();
    #pragma unroll
    for (int i = 0; i < 16; ++i) {
      int e = base + i * 256 + t;
      if (e < ne) {
        int r = ((const int2*)b.idx)[e].x;
        atomicAdd(&hist[r >> 8], 1);
      }
    }
    __syncthreads();
    if (t < nb) {
      int h = hist[t];
      if (h) atomicAdd(&b.bucketTotal[t], h);
    }
    return;
  }

  // ---- gemm body ----
  const int w = t >> 6, l = t & 63;
  const int c = l & 15, g = l >> 4;
  const int row0 = blockIdx.x * 128;
  if (row0 >= n_rows) return;

  auto stage = [&](int ks, int buf) {
    #pragma unroll
    for (int i = 0; i < 4; ++i) {
      int row = i * 32 + (t >> 3);
      int gr = row0 + row; if (gr > n_rows - 1) gr = n_rows - 1;
      int kb = ((t & 7) * 16) ^ ((row & 7) << 4);   // swizzled byte within 128B row
      const float* src = b.X + (size_t)gr * D_IN + ks * 32 + (kb >> 2);
      __builtin_amdgcn_global_load_lds(
          (const __attribute__((address_space(1))) uint32_t*)src,
          (__attribute__((address_space(3))) uint32_t*)&sX[buf][i * 4096 + t * 16],
          16, 0, 0);
    }
  };

  const uint4* Bp = (const uint4*)WT3;

  f32x4 acc[2][8];
  #pragma unroll
  for (int i = 0; i < 2; ++i)
    #pragma unroll
    for (int j = 0; j < 8; ++j) acc[i][j] = (f32x4){0.f, 0.f, 0.f, 0.f};

  stage(0, 0);
  asm volatile("s_waitcnt vmcnt(0)" ::: "memory");
  __syncthreads();

  for (int ks = 0; ks < 8; ++ks) {
    int buf = ks & 1;
    uint4 bu[8];
    #pragma unroll
    for (int nf = 0; nf < 8; ++nf)
      bu[nf] = Bp[(ks * 4 + g) * 128 + nf * 16 + c];
    if (ks < 7) stage(ks + 1, buf ^ 1);

    Frag A[2];
    #pragma unroll
    for (int rf = 0; rf < 2; ++rf) {
      int row = w * 32 + rf * 16 + c;
      const uint8_t* base = &sX[buf][row * 128];
      int swz = (row & 7) << 4;
      float4 x0 = *(const float4*)(base + ((g * 16) ^ swz));
      float4 x1 = *(const float4*)(base + ((64 + g * 16) ^ swz));
      A[rf].u[0] = cvt_pk_bf16(x0.x, x0.y);
      A[rf].u[1] = cvt_pk_bf16(x0.z, x0.w);
      A[rf].u[2] = cvt_pk_bf16(x1.x, x1.y);
      A[rf].u[3] = cvt_pk_bf16(x1.z, x1.w);
    }

    #pragma unroll
    for (int nf = 0; nf < 8; ++nf) {
      Frag B;
      B.u[0] = bu[nf].x; B.u[1] = bu[nf].y; B.u[2] = bu[nf].z; B.u[3] = bu[nf].w;
      acc[0][nf] = __builtin_amdgcn_mfma_f32_16x16x32_bf16(A[0].v, B.v, acc[0][nf], 0, 0, 0);
      acc[1][nf] = __builtin_amdgcn_mfma_f32_16x16x32_bf16(A[1].v, B.v, acc[1][nf], 0, 0, 0);
    }

    if (ks < 7) {
      asm volatile("s_waitcnt vmcnt(0)" ::: "memory");
      __syncthreads();
    }
  }

  #pragma unroll
  for (int rf = 0; rf < 2; ++rf)
    #pragma unroll
    for (int nf = 0; nf < 8; ++nf)
      #pragma unroll
      for (int r = 0; r < 4; ++r) {
        float v = acc[rf][nf][r];
        float o = __shfl_xor(v, 1);
        uint32_t pk = cvt_pk_bf16(v, o);       // valid at even c: cols (c, c+1)
        uint32_t pk2 = __shfl_xor(pk, 2);      // partner: cols (c+2, c+3)
        int row_g = row0 + w * 32 + rf * 16 + 4 * g + r;
        if ((c & 3) == 0 && row_g < n_rows) {
          uint2 d; d.x = pk; d.y = pk2;
          *(uint2*)(b.H + (size_t)row_g * D_OUT + nf * 16 + c) = d;
        }
      }
}

__global__ __launch_bounds__(256) void bucket_scan_kernel(Branch b0, Branch b1, int nb, int n, int ne) {
  Branch b = blockIdx.y ? b1 : b0;
  const int tid = threadIdx.x;
  int v = (tid < nb) ? b.bucketTotal[tid] : 0;
  int excl = block_scan256_excl(v, tid);
  if (tid <= nb) b.bucketBase[tid] = excl;
  if (tid < nb)  b.bucketCur[tid]  = excl;
  if (tid == 0)  b.ptr[n] = ne;
}

// ---------------- bin: bucket-grouped scatter ----------------
__global__ __launch_bounds__(256) void bin_kernel(Branch b0, Branch b1, int ne, int nb) {
  Branch b = blockIdx.y ? b1 : b0;
  __shared__ int hist[NB_MAX];
  __shared__ int lcur[NB_MAX];
  __shared__ int gbase[NB_MAX];
  const int tid = threadIdx.x;
  const int base = blockIdx.x * 4096;
  if (tid < nb) hist[tid] = 0;
  __syncthreads();
  uint64_t kv2[16];
  int bkt[16];
  #pragma unroll
  for (int i = 0; i < 16; ++i) {
    int e = base + i * 256 + tid;
    bkt[i] = -1;
    if (e < ne) {
      int2 rc = ((const int2*)b.idx)[e];
      uint32_t v = __float_as_uint(b.val[e]);
      kv2[i] = ((uint64_t)v << 32) | ((uint32_t)rc.x << 16) | (uint32_t)rc.y;
      bkt[i] = rc.x >> 8;
      atomicAdd(&hist[bkt[i]], 1);
    }
  }
  __syncthreads();
  if (tid < nb) {
    int h = hist[tid];
    gbase[tid] = h ? atomicAdd(&b.bucketCur[tid], h) : 0;
    lcur[tid] = 0;
  }
  __syncthreads();
  #pragma unroll
  for (int i = 0; i < 16; ++i) {
    if (bkt[i] >= 0) {
      int dst = gbase[bkt[i]] + atomicAdd(&lcur[bkt[i]], 1);
      b.kv2[dst] = kv2[i];
    }
  }
}

// ---------------- per-bucket CSR finalize: 4B entries (val_bf16<<16 | col) ----------------
__global__ __launch_bounds__(256) void bucket_csr_kernel(Branch b0, Branch b1, int n) {
  Branch b = blockIdx.y ? b1 : b0;
  const int bkt = blockIdx.x;
  const int tid = threadIdx.x;
  const int beg = b.bucketBase[bkt], end = b.bucketBase[bkt + 1];
  __shared__ int hist[256];
  __shared__ int cur[256];
  hist[tid] = 0;
  __syncthreads();
  for (int e = beg + tid; e < end; e += 256)
    atomicAdd(&hist[(int)((b.kv2[e] >> 16) & 0xFF)], 1);
  __syncthreads();
  int v = hist[tid];
  int excl = block_scan256_excl(v, tid);
  cur[tid] = beg + excl;
  int row = bkt * 256 + tid;
  if (row < n) b.ptr[row] = beg + excl;
  __syncthreads();
  for (int e = beg + tid; e < end; e += 256) {
    uint64_t kv2 = b.kv2[e];
    int r = (int)((kv2 >> 16) & 0xFF);
    uint32_t u = (uint32_t)(kv2 >> 32);
    uint32_t vbf = (u + 0x7FFFu + ((u >> 16) & 1u)) & 0xFFFF0000u;  // RNE bf16 in high16
    int pos = atomicAdd(&cur[r], 1);
    b.csr4[pos] = vbf | (uint32_t)(kv2 & 0xFFFFu);
  }
}

// ---------------- per-row gather + relu (single pass, flat H, deep MLP) ----------------
// 32 lanes per row, 8 rows per block; XCD routing: branch = (bid&7)>>2  [XCD = bid % 8]
__global__ __launch_bounds__(256) void gather_kernel(Branch b0, Branch b1, int n_rows) {
  const int bid = blockIdx.x;
  const int br  = (bid & 7) >> 2;
  const int local = (bid >> 3) * 4 + (bid & 3);
  Branch b = br ? b1 : b0;
  int row = local * 8 + (threadIdx.x >> 5);
  if (row >= n_rows) return;
  int lane2 = (threadIdx.x & 31) * 2;
  const uint32_t* H32 = (const uint32_t*)b.H;
  int beg = b.ptr[row], end = b.ptr[row + 1];
  float4 acc = make_float4(0.f, 0.f, 0.f, 0.f);

  auto fma_h = [&](uint32_t k, uint2 h) {
    float v = __uint_as_float(k & 0xFFFF0000u);
    float h0 = __uint_as_float(h.x << 16);
    float h1 = __uint_as_float(h.x & 0xFFFF0000u);
    float h2 = __uint_as_float(h.y << 16);
    float h3 = __uint_as_float(h.y & 0xFFFF0000u);
    acc.x = fmaf(h0, v, acc.x); acc.y = fmaf(h1, v, acc.y);
    acc.z = fmaf(h2, v, acc.z); acc.w = fmaf(h3, v, acc.w);
  };

  int e = beg;
  for (; e + 16 <= end; e += 16) {
    uint32_t k[16];
    #pragma unroll
    for (int i = 0; i < 16; ++i) k[i] = b.csr4[e + i];
    uint2 h[16];
    #pragma unroll
    for (int i = 0; i < 16; ++i)
      h[i] = *(const uint2*)(H32 + (size_t)(k[i] & 0xFFFFu) * 64 + lane2);
    #pragma unroll
    for (int i = 0; i < 16; ++i) fma_h(k[i], h[i]);
  }
  if (e + 8 <= end) {
    uint32_t k[8];
    #pragma unroll
    for (int i = 0; i < 8; ++i) k[i] = b.csr4[e + i];
    uint2 h[8];
    #pragma unroll
    for (int i = 0; i < 8; ++i)
      h[i] = *(const uint2*)(H32 + (size_t)(k[i] & 0xFFFFu) * 64 + lane2);
    #pragma unroll
    for (int i = 0; i < 8; ++i) fma_h(k[i], h[i]);
    e += 8;
  }
  for (; e < end; ++e) {
    uint32_t k = b.csr4[e];
    uint2 h = *(const uint2*)(H32 + (size_t)(k & 0xFFFFu) * 64 + lane2);
    fma_h(k, h);
  }

  float4 o;
  o.x = fmaxf(acc.x, 0.f); o.y = fmaxf(acc.y, 0.f);
  o.z = fmaxf(acc.z, 0.f); o.w = fmaxf(acc.w, 0.f);
  *(float4*)&b.out[(size_t)row * D_OUT + (threadIdx.x & 31) * 4] = o;
}

extern "C" void kernel_launch(void* const* d_in, const int* in_sizes, int n_in,
                              void* d_out, int out_size, void* d_ws, size_t ws_size,
                              hipStream_t stream) {
  const float* inp_s = (const float*)d_in[0];
  const float* inp_t = (const float*)d_in[1];
  const int*   idx_s = (const int*)d_in[2];
  const float* val_s = (const float*)d_in[3];
  const int*   idx_t = (const int*)d_in[4];
  const float* val_t = (const float*)d_in[5];
  const float* W     = (const float*)d_in[6];
  float* out = (float*)d_out;

  const int n  = in_sizes[0] / D_IN;   // 50000
  const int ne = in_sizes[3];          // 1600000
  const int nb = (n + 255) >> 8;       // 196

  char* p = (char*)d_ws;
  auto alloc = [&](size_t bytes) -> char* {
    char* r = p;
    p += (bytes + 255) & ~(size_t)255;
    return r;
  };
  uint16_t* H_s    = (uint16_t*)alloc((size_t)n * D_OUT * 2);
  uint16_t* H_t    = (uint16_t*)alloc((size_t)n * D_OUT * 2);
  uint16_t* WT3    = (uint16_t*)alloc((size_t)128 * 256 * 2);
  int* ptr_s       = (int*)alloc((size_t)(n + 1) * 4);
  int* ptr_t       = (int*)alloc((size_t)(n + 1) * 4);
  int* btotal      = (int*)alloc((size_t)2 * NB_MAX * 4);
  int* btotal_s    = btotal;
  int* btotal_t    = btotal + NB_MAX;
  int* bbase_s     = (int*)alloc((size_t)(NB_MAX + 1) * 4);
  int* bbase_t     = (int*)alloc((size_t)(NB_MAX + 1) * 4);
  int* bcur_s      = (int*)alloc(NB_MAX * 4);
  int* bcur_t      = (int*)alloc(NB_MAX * 4);
  uint64_t* kv2_s  = (uint64_t*)alloc((size_t)ne * 8);
  uint64_t* kv2_t  = (uint64_t*)alloc((size_t)ne * 8);
  uint32_t* c4_s   = (uint32_t*)alloc((size_t)ne * 4);
  uint32_t* c4_t   = (uint32_t*)alloc((size_t)ne * 4);

  Branch bs = { inp_s, idx_s, val_s, H_s, ptr_s, btotal_s, bbase_s, bcur_s, kv2_s, c4_s, out };
  Branch bt = { inp_t, idx_t, val_t, H_t, ptr_t, btotal_t, bbase_t, bcur_t, kv2_t, c4_t,
                out + (size_t)n * D_OUT };

  const int nblkE = (ne + 4095) / 4096;            // 391
  const int nblkG = (n + 127) / 128;               // 391
  const int nblkF = nblkE > nblkG ? nblkE : nblkG;
  const int bpb   = (((n + 7) / 8) + 3) & ~3;      // gather blocks per branch, %4==0

  hipMemsetAsync(btotal, 0, (size_t)2 * NB_MAX * 4, stream);
  wprep3_kernel<<<dim3(128), 256, 0, stream>>>(W, WT3);
  gemm_count_kernel<<<dim3(nblkF, 2, 2), 256, 0, stream>>>(WT3, bs, bt, n, ne, nb);
  bucket_scan_kernel<<<dim3(1, 2), 256, 0, stream>>>(bs, bt, nb, n, ne);
  bin_kernel<<<dim3(nblkE, 2), 256, 0, stream>>>(bs, bt, ne, nb);
  bucket_csr_kernel<<<dim3(nb, 2), 256, 0, stream>>>(bs, bt, n);
  gather_kernel<<<dim3(2 * bpb), 256, 0, stream>>>(bs, bt, n);
}